// Round 6
// baseline (491.824 us; speedup 1.0000x reference)
//
#include <hip/hip_runtime.h>
#include <math.h>

#define BATCH 2048
#define LDIM 64
#define EDIM 256
#define UDIM 512

typedef __attribute__((ext_vector_type(8))) _Float16 half8;
typedef __attribute__((ext_vector_type(4))) float floatx4;

__device__ inline float tanh_fast(float x) {
    float t = __builtin_amdgcn_exp2f(x * 2.88539008177792681f);
    return 1.f - 2.f * __builtin_amdgcn_rcpf(t + 1.f);
}
__device__ inline half8 cvt8(float4 f0, float4 f1) {
    half8 h;
    h[0] = (_Float16)f0.x; h[1] = (_Float16)f0.y;
    h[2] = (_Float16)f0.z; h[3] = (_Float16)f0.w;
    h[4] = (_Float16)f1.x; h[5] = (_Float16)f1.y;
    h[6] = (_Float16)f1.z; h[7] = (_Float16)f1.w;
    return h;
}
// B-fragment pointer: layout [kc][ntg(32)][lane(64)][8 fp16]
__device__ inline const half8* bfrag(const unsigned short* F, int kc, int ntg, int l) {
    return (const half8*)(F + ((((size_t)kc * 32 + ntg) * 64 + l) << 3));
}

// ---- prep: W[K][512] fp32 -> fp16 B-fragments via coalesced LDS slab. ----
__global__ __launch_bounds__(256) void prep_frag(const float* __restrict__ W1,
                                                 const float* __restrict__ W2,
                                                 unsigned short* __restrict__ F1,
                                                 unsigned short* __restrict__ F2) {
    __shared__ float S[32 * 128];
    int bid = blockIdx.x;
    const float* W; unsigned short* F; int kc, grp;
    if (bid < 32) { W = W1; F = F1; kc = bid >> 2; grp = bid & 3; }
    else { bid -= 32; W = W2; F = F2; kc = bid >> 2; grp = bid & 3; }
    const int tid = threadIdx.x;
    const float* src = W + (size_t)kc * 32 * UDIM + grp * 128;
    float4* Sv = (float4*)S;
#pragma unroll
    for (int i = 0; i < 4; ++i) {
        int f = tid + i * 256;
        int k = f >> 5, c4 = f & 31;
        Sv[f] = *(const float4*)(src + (size_t)k * UDIM + c4 * 4);
    }
    __syncthreads();
#pragma unroll
    for (int i = 0; i < 2; ++i) {
        int u = tid + i * 256;
        int lane = u & 63, ntl = u >> 6;
        int n_loc = ntl * 16 + (lane & 15);
        int k0 = (lane >> 4) * 8;
        half8 h;
#pragma unroll
        for (int j = 0; j < 8; ++j)
            h[j] = (_Float16)S[(k0 + j) * 128 + n_loc];
        int ntg = grp * 8 + ntl;
        *(half8*)(F + (((size_t)kc * 32 + ntg) * 64 + lane) * 8) = h;
    }
}

// ---- prep_ph: ph = hidden @ W2 + b1 + b2 via fp16 MFMA. M=16/block, 128 blocks. ----
__global__ __launch_bounds__(256) void prep_ph(const float* __restrict__ hidden,
                                               const unsigned short* __restrict__ F2,
                                               const float* __restrict__ b1,
                                               const float* __restrict__ b2,
                                               float* __restrict__ ph) {
    const int tid = threadIdx.x;
    const int w = tid >> 6;
    const int l = tid & 63;
    const int r0 = blockIdx.x * 16;

    floatx4 acc[8];
#pragma unroll
    for (int i = 0; i < 8; ++i) acc[i] = (floatx4){0.f, 0.f, 0.f, 0.f};

    const float* ap = hidden + (size_t)(r0 + (l & 15)) * UDIM + ((l >> 4) << 3);

    float4 a0 = *(const float4*)(ap);
    float4 a1 = *(const float4*)(ap + 4);
    half8 B[8];
#pragma unroll
    for (int nt = 0; nt < 8; ++nt) B[nt] = *bfrag(F2, 0, w * 8 + nt, l);

    for (int kc = 0; kc < 16; ++kc) {
        half8 a = cvt8(a0, a1);
        float4 n0, n1; half8 NB[8];
        if (kc < 15) {
            n0 = *(const float4*)(ap + (kc + 1) * 32);
            n1 = *(const float4*)(ap + (kc + 1) * 32 + 4);
#pragma unroll
            for (int nt = 0; nt < 8; ++nt) NB[nt] = *bfrag(F2, kc + 1, w * 8 + nt, l);
        }
#pragma unroll
        for (int nt = 0; nt < 8; ++nt)
            acc[nt] = __builtin_amdgcn_mfma_f32_16x16x32_f16(a, B[nt], acc[nt], 0, 0, 0);
        if (kc < 15) {
            a0 = n0; a1 = n1;
#pragma unroll
            for (int nt = 0; nt < 8; ++nt) B[nt] = NB[nt];
        }
    }
#pragma unroll
    for (int nt = 0; nt < 8; ++nt) {
        const int n = (w * 8 + nt) * 16 + (l & 15);
        const float bias = b1[n] + b2[n];
#pragma unroll
        for (int r = 0; r < 4; ++r) {
            const int m = (l >> 4) * 4 + r;
            ph[(size_t)(r0 + m) * UDIM + n] = acc[nt][r] + bias;
        }
    }
}

// ---- main: block = 1 batch (round-1 structure), 512 threads / 8 waves.
// acc chunked over N (2 passes of 64x32 per wave, acc[2][4]=32 regs) so
// VGPR<=85 -> 3 blocks/CU (launch_bounds(512,6)).  Tail: wave-redundant
// softmax + shfl-broadcast context -> only 2 barriers total.
__global__ __launch_bounds__(512, 6) void attn_main(
    const float* __restrict__ feat, const unsigned short* __restrict__ F1,
    const float* __restrict__ ph, const float* __restrict__ Vw,
    const float* __restrict__ bv,
    float* __restrict__ ctx_out, float* __restrict__ w_out)
{
    __shared__ unsigned short lA[8 * 4 * 64 * 8];  // 32 KB: [kc][mt][lane^kc][8]
    __shared__ float phl[512];
    __shared__ float Vl[512];
    __shared__ float scp[8][64];

    const int tid = threadIdx.x;
    const int w = tid >> 6;
    const int l = tid & 63;
    const size_t b = blockIdx.x;
    const float* fb = feat + b * (LDIM * EDIM);

    const float bvv = bv[0];

    // ---- staging: 2 units/thread, 4 contiguous float4 each ----
    float4 f4[2][4];
#pragma unroll
    for (int p = 0; p < 2; ++p) {
        const int u = tid + 512 * p;
        const float4* gp = (const float4*)(fb + (u >> 4) * EDIM + (u & 15) * 16);
        f4[p][0] = gp[0]; f4[p][1] = gp[1]; f4[p][2] = gp[2]; f4[p][3] = gp[3];
    }
    phl[tid] = ph[b * UDIM + tid];
    Vl[tid]  = Vw[tid];

#pragma unroll
    for (int p = 0; p < 2; ++p) {
        const int u  = tid + 512 * p;
        const int r  = u >> 4, kc = (u & 15) >> 1, o = (u & 1) * 2;
        const int mt = r >> 4, rr = r & 15;
        const int base = (kc * 4 + mt) * 64;
        *(half8*)&lA[(base + ((o * 16 + rr) ^ kc)) * 8]       = cvt8(f4[p][0], f4[p][1]);
        *(half8*)&lA[(base + (((o + 1) * 16 + rr) ^ kc)) * 8] = cvt8(f4[p][2], f4[p][3]);
    }

    __syncthreads();  // barrier 1: lA/phl/Vl staged

    // ---- GEMM in 2 N-chunks; epilogue fused per chunk into sv ----
    float sv[4][4];
#pragma unroll
    for (int mt = 0; mt < 4; ++mt)
#pragma unroll
        for (int r = 0; r < 4; ++r) sv[mt][r] = 0.f;

    for (int nc = 0; nc < 2; ++nc) {
        floatx4 acc[2][4];  // [nt][mt] -- 32 VGPRs
#pragma unroll
        for (int x = 0; x < 2; ++x)
#pragma unroll
            for (int y = 0; y < 4; ++y) acc[x][y] = (floatx4){0.f, 0.f, 0.f, 0.f};

        for (int kc = 0; kc < 8; ++kc) {
            half8 Bc[2];
#pragma unroll
            for (int nt = 0; nt < 2; ++nt)
                Bc[nt] = *bfrag(F1, kc, w * 4 + nc * 2 + nt, l);
#pragma unroll
            for (int mt = 0; mt < 4; ++mt) {
                const half8 a = *(const half8*)&lA[((kc * 4 + mt) * 64 + (l ^ kc)) * 8];
#pragma unroll
                for (int nt = 0; nt < 2; ++nt)
                    acc[nt][mt] = __builtin_amdgcn_mfma_f32_16x16x32_f16(
                        a, Bc[nt], acc[nt][mt], 0, 0, 0);
            }
        }
        // fused epilogue for this chunk
#pragma unroll
        for (int nt = 0; nt < 2; ++nt) {
            const int n = (w * 4 + nc * 2 + nt) * 16 + (l & 15);
            const float phn = phl[n];
            const float vn  = Vl[n];
#pragma unroll
            for (int mt = 0; mt < 4; ++mt)
#pragma unroll
                for (int r = 0; r < 4; ++r)
                    sv[mt][r] += tanh_fast(acc[nt][mt][r] + phn) * vn;
        }
    }

    // per-row score partials -> scp
#pragma unroll
    for (int mt = 0; mt < 4; ++mt)
#pragma unroll
        for (int r = 0; r < 4; ++r) {
            float v = sv[mt][r];
            v += __shfl_xor(v, 1);
            v += __shfl_xor(v, 2);
            v += __shfl_xor(v, 4);
            v += __shfl_xor(v, 8);
            if ((l & 15) == 0) scp[w][mt * 16 + (l >> 4) * 4 + r] = v;
        }
    __syncthreads();  // barrier 2: scp complete

    // ---- softmax, computed redundantly by ALL waves (lane l owns row l) ----
    float s = bvv;
#pragma unroll
    for (int wv = 0; wv < 8; ++wv) s += scp[wv][l];
    float m = s;
    m = fmaxf(m, __shfl_xor(m, 32));
    m = fmaxf(m, __shfl_xor(m, 16));
    m = fmaxf(m, __shfl_xor(m, 8));
    m = fmaxf(m, __shfl_xor(m, 4));
    m = fmaxf(m, __shfl_xor(m, 2));
    m = fmaxf(m, __shfl_xor(m, 1));
    float e = __builtin_amdgcn_exp2f((s - m) * 1.44269504088896341f);
    float sum = e;
    sum += __shfl_xor(sum, 32);
    sum += __shfl_xor(sum, 16);
    sum += __shfl_xor(sum, 8);
    sum += __shfl_xor(sum, 4);
    sum += __shfl_xor(sum, 2);
    sum += __shfl_xor(sum, 1);
    const float wgt = e / sum;
    if (w == 0) w_out[b * LDIM + l] = wgt;

    // ---- context: wave w owns e-cols [32w,32w+32); weights via shfl ----
    {
        const int e0 = (w << 5) + (l & 31);
        const int h  = l >> 5;               // row half
        float c = 0.f;
#pragma unroll 8
        for (int r = 0; r < 32; ++r) {
            const int ll = h * 32 + r;
            const float wl = __shfl(wgt, ll);
            c = fmaf(wl, fb[ll * EDIM + e0], c);
        }
        c += __shfl_xor(c, 32);              // combine row halves
        if (l < 32)
            ctx_out[b * EDIM + e0] = c;
    }
}

extern "C" void kernel_launch(void* const* d_in, const int* in_sizes, int n_in,
                              void* d_out, int out_size, void* d_ws, size_t ws_size,
                              hipStream_t stream) {
    const float* features = (const float*)d_in[0];
    const float* hidden   = (const float*)d_in[1];
    const float* W1       = (const float*)d_in[2];
    const float* b1       = (const float*)d_in[3];
    const float* W2       = (const float*)d_in[4];
    const float* b2       = (const float*)d_in[5];
    const float* Vw       = (const float*)d_in[6];
    const float* bv       = (const float*)d_in[7];

    float* ctx_out = (float*)d_out;
    float* w_out   = (float*)d_out + (size_t)BATCH * EDIM;

    float* ph = (float*)d_ws;
    unsigned short* F1 = (unsigned short*)(ph + (size_t)BATCH * UDIM);
    unsigned short* F2 = F1 + (size_t)8 * 32 * 64 * 8;

    prep_frag<<<dim3(96), dim3(256), 0, stream>>>(W1, W2, F1, F2);
    prep_ph<<<dim3(128), dim3(256), 0, stream>>>(hidden, F2, b1, b2, ph);
    attn_main<<<dim3(BATCH), dim3(512), 0, stream>>>(
        features, F1, ph, Vw, bv, ctx_out, w_out);
}

// Round 8
// 255.339 us; speedup vs baseline: 1.9262x; 1.9262x over previous
//
#include <hip/hip_runtime.h>
#include <math.h>

#define BATCH 2048
#define LDIM 64
#define EDIM 256
#define UDIM 512

typedef __attribute__((ext_vector_type(8))) _Float16 half8;
typedef __attribute__((ext_vector_type(4))) _Float16 half4;
typedef __attribute__((ext_vector_type(4))) float floatx4;

__device__ inline float tanh_fast(float x) {
    float t = __builtin_amdgcn_exp2f(x * 2.88539008177792681f);
    return 1.f - 2.f * __builtin_amdgcn_rcpf(t + 1.f);
}
__device__ inline half8 cvt8(float4 f0, float4 f1) {
    half8 h;
    h[0] = (_Float16)f0.x; h[1] = (_Float16)f0.y;
    h[2] = (_Float16)f0.z; h[3] = (_Float16)f0.w;
    h[4] = (_Float16)f1.x; h[5] = (_Float16)f1.y;
    h[6] = (_Float16)f1.z; h[7] = (_Float16)f1.w;
    return h;
}
__device__ inline half4 cvt4(float4 f) {
    half4 h;
    h[0] = (_Float16)f.x; h[1] = (_Float16)f.y;
    h[2] = (_Float16)f.z; h[3] = (_Float16)f.w;
    return h;
}
// B-fragment pointer: layout [kc][ntg(32)][lane(64)][8 fp16]
__device__ inline const half8* bfrag(const unsigned short* F, int kc, int ntg, int l) {
    return (const half8*)(F + ((((size_t)kc * 32 + ntg) * 64 + l) << 3));
}

// ---- prep: W[K][512] fp32 -> fp16 B-fragments via coalesced LDS slab. ----
__global__ __launch_bounds__(256) void prep_frag(const float* __restrict__ W1,
                                                 const float* __restrict__ W2,
                                                 unsigned short* __restrict__ F1,
                                                 unsigned short* __restrict__ F2) {
    __shared__ float S[32 * 128];
    int bid = blockIdx.x;
    const float* W; unsigned short* F; int kc, grp;
    if (bid < 32) { W = W1; F = F1; kc = bid >> 2; grp = bid & 3; }
    else { bid -= 32; W = W2; F = F2; kc = bid >> 2; grp = bid & 3; }
    const int tid = threadIdx.x;
    const float* src = W + (size_t)kc * 32 * UDIM + grp * 128;
    float4* Sv = (float4*)S;
#pragma unroll
    for (int i = 0; i < 4; ++i) {
        int f = tid + i * 256;
        int k = f >> 5, c4 = f & 31;
        Sv[f] = *(const float4*)(src + (size_t)k * UDIM + c4 * 4);
    }
    __syncthreads();
#pragma unroll
    for (int i = 0; i < 2; ++i) {
        int u = tid + i * 256;
        int lane = u & 63, ntl = u >> 6;
        int n_loc = ntl * 16 + (lane & 15);
        int k0 = (lane >> 4) * 8;
        half8 h;
#pragma unroll
        for (int j = 0; j < 8; ++j)
            h[j] = (_Float16)S[(k0 + j) * 128 + n_loc];
        int ntg = grp * 8 + ntl;
        *(half8*)(F + (((size_t)kc * 32 + ntg) * 64 + lane) * 8) = h;
    }
}

// ---- prep_ph: ph = hidden @ W2 + b1 + b2 via fp16 MFMA. M=16/block, 128 blocks. ----
__global__ __launch_bounds__(256) void prep_ph(const float* __restrict__ hidden,
                                               const unsigned short* __restrict__ F2,
                                               const float* __restrict__ b1,
                                               const float* __restrict__ b2,
                                               float* __restrict__ ph) {
    const int tid = threadIdx.x;
    const int w = tid >> 6;
    const int l = tid & 63;
    const int r0 = blockIdx.x * 16;

    floatx4 acc[8];
#pragma unroll
    for (int i = 0; i < 8; ++i) acc[i] = (floatx4){0.f, 0.f, 0.f, 0.f};

    const float* ap = hidden + (size_t)(r0 + (l & 15)) * UDIM + ((l >> 4) << 3);

    float4 a0 = *(const float4*)(ap);
    float4 a1 = *(const float4*)(ap + 4);
    half8 B[8];
#pragma unroll
    for (int nt = 0; nt < 8; ++nt) B[nt] = *bfrag(F2, 0, w * 8 + nt, l);

    for (int kc = 0; kc < 16; ++kc) {
        half8 a = cvt8(a0, a1);
        float4 n0, n1; half8 NB[8];
        if (kc < 15) {
            n0 = *(const float4*)(ap + (kc + 1) * 32);
            n1 = *(const float4*)(ap + (kc + 1) * 32 + 4);
#pragma unroll
            for (int nt = 0; nt < 8; ++nt) NB[nt] = *bfrag(F2, kc + 1, w * 8 + nt, l);
        }
#pragma unroll
        for (int nt = 0; nt < 8; ++nt)
            acc[nt] = __builtin_amdgcn_mfma_f32_16x16x32_f16(a, B[nt], acc[nt], 0, 0, 0);
        if (kc < 15) {
            a0 = n0; a1 = n1;
#pragma unroll
            for (int nt = 0; nt < 8; ++nt) B[nt] = NB[nt];
        }
    }
#pragma unroll
    for (int nt = 0; nt < 8; ++nt) {
        const int n = (w * 8 + nt) * 16 + (l & 15);
        const float bias = b1[n] + b2[n];
#pragma unroll
        for (int r = 0; r < 4; ++r) {
            const int m = (l >> 4) * 4 + r;
            ph[(size_t)(r0 + m) * UDIM + n] = acc[nt][r] + bias;
        }
    }
}

// ---- main: block = 1 batch, 512 threads / 8 waves (round-1 shape), but the
// A-tile is staged in per-kc SLABS pipelined through the GEMM loop:
//   iter kc: load 16B of slab kc+1 (4 VGPRs, transient) -> Bc loads + MFMA(kc)
//            -> cvt + ds_write slab kc+1 -> __syncthreads.
// Keeps HBM busy through the whole GEMM phase instead of one up-front burst,
// at zero persistent register cost (the f4[2][4]=32-reg staging is gone).
__global__ __launch_bounds__(512, 4) void attn_main(
    const float* __restrict__ feat, const unsigned short* __restrict__ F1,
    const float* __restrict__ ph, const float* __restrict__ Vw,
    const float* __restrict__ bv,
    float* __restrict__ ctx_out, float* __restrict__ w_out)
{
    __shared__ _Float16 lS[2][4][64][8];  // 2 slots x [mt][lane'][8] = 8 KB
    __shared__ float phl[512];
    __shared__ float Vl[512];
    __shared__ float scp[8][64];
    __shared__ float wsm[64];
    __shared__ float ctxp[2][256];

    const int tid = threadIdx.x;
    const int w = tid >> 6;
    const int l = tid & 63;
    const size_t b = blockIdx.x;
    const float* fb = feat + b * (LDIM * EDIM);

    // staging role of this thread: row r, 4-col quad q of each 32-col slab
    const int r  = tid >> 3, q = tid & 7;
    const int mt_s = r >> 4;
    const int fl   = (q >> 1) * 16 + (r & 15);  // fragment lane' (pre-XOR)
    const int h4   = (q & 1) * 4;               // half offset within half8

    // prologue: stage slab 0 + phl/Vl
    {
        float4 g = *(const float4*)(fb + r * EDIM + q * 4);
        phl[tid] = ph[b * UDIM + tid];
        Vl[tid]  = Vw[tid];
        *(half4*)&lS[0][mt_s][fl ^ 0][h4] = cvt4(g);
    }
    __syncthreads();

    floatx4 acc[4][4];  // [nt][mt]
#pragma unroll
    for (int i = 0; i < 4; ++i)
#pragma unroll
        for (int j = 0; j < 4; ++j) acc[i][j] = (floatx4){0.f, 0.f, 0.f, 0.f};

    for (int kc = 0; kc < 8; ++kc) {
        // issue next slab's 16B load first (HBM latency covered by Bc+MFMA)
        float4 g;
        if (kc < 7)
            g = *(const float4*)(fb + r * EDIM + (kc + 1) * 32 + q * 4);

        half8 Bc[4];
#pragma unroll
        for (int nt = 0; nt < 4; ++nt) Bc[nt] = *bfrag(F1, kc, w * 4 + nt, l);
#pragma unroll
        for (int mt = 0; mt < 4; ++mt) {
            const half8 a = *(const half8*)&lS[kc & 1][mt][l ^ kc][0];
#pragma unroll
            for (int nt = 0; nt < 4; ++nt)
                acc[nt][mt] = __builtin_amdgcn_mfma_f32_16x16x32_f16(
                    a, Bc[nt], acc[nt][mt], 0, 0, 0);
        }

        if (kc < 7) {
            // land slab kc+1 into the other slot; barrier publishes it
            *(half4*)&lS[(kc + 1) & 1][mt_s][fl ^ (kc + 1)][h4] = cvt4(g);
            __syncthreads();
        }
    }

    // ---- epilogue: tanh(acc + ph) * V -> per-row score partials ----
    float sv[4][4];
#pragma unroll
    for (int mt = 0; mt < 4; ++mt)
#pragma unroll
        for (int rr = 0; rr < 4; ++rr) sv[mt][rr] = 0.f;
#pragma unroll
    for (int nt = 0; nt < 4; ++nt) {
        const int n = (w * 4 + nt) * 16 + (l & 15);
        const float phn = phl[n];
        const float vn  = Vl[n];
#pragma unroll
        for (int mt = 0; mt < 4; ++mt)
#pragma unroll
            for (int rr = 0; rr < 4; ++rr)
                sv[mt][rr] += tanh_fast(acc[nt][mt][rr] + phn) * vn;
    }
#pragma unroll
    for (int mt = 0; mt < 4; ++mt)
#pragma unroll
        for (int rr = 0; rr < 4; ++rr) {
            float v = sv[mt][rr];
            v += __shfl_xor(v, 1);
            v += __shfl_xor(v, 2);
            v += __shfl_xor(v, 4);
            v += __shfl_xor(v, 8);
            if ((l & 15) == 0) scp[w][mt * 16 + (l >> 4) * 4 + rr] = v;
        }
    __syncthreads();

    // ---- softmax over L=64 (first 64 threads) ----
    if (tid < 64) {
        float s = bv[0];
#pragma unroll
        for (int wv = 0; wv < 8; ++wv) s += scp[wv][tid];
        float m = s;
        m = fmaxf(m, __shfl_xor(m, 32));
        m = fmaxf(m, __shfl_xor(m, 16));
        m = fmaxf(m, __shfl_xor(m, 8));
        m = fmaxf(m, __shfl_xor(m, 4));
        m = fmaxf(m, __shfl_xor(m, 2));
        m = fmaxf(m, __shfl_xor(m, 1));
        float e = __builtin_amdgcn_exp2f((s - m) * 1.44269504088896341f);
        float sum = e;
        sum += __shfl_xor(sum, 32);
        sum += __shfl_xor(sum, 16);
        sum += __shfl_xor(sum, 8);
        sum += __shfl_xor(sum, 4);
        sum += __shfl_xor(sum, 2);
        sum += __shfl_xor(sum, 1);
        float wgt = e / sum;
        wsm[tid] = wgt;
        w_out[b * LDIM + tid] = wgt;
    }
    __syncthreads();

    // ---- context: halves of rows per thread-group (fb is L2-hot) ----
    {
        const int e = tid & 255, h = tid >> 8;
        float c = 0.f;
#pragma unroll 8
        for (int ll = h * 32; ll < h * 32 + 32; ++ll)
            c = fmaf(wsm[ll], fb[ll * EDIM + e], c);
        ctxp[h][e] = c;
    }
    __syncthreads();
    if (tid < 256)
        ctx_out[b * EDIM + tid] = ctxp[0][tid] + ctxp[1][tid];
}

extern "C" void kernel_launch(void* const* d_in, const int* in_sizes, int n_in,
                              void* d_out, int out_size, void* d_ws, size_t ws_size,
                              hipStream_t stream) {
    const float* features = (const float*)d_in[0];
    const float* hidden   = (const float*)d_in[1];
    const float* W1       = (const float*)d_in[2];
    const float* b1       = (const float*)d_in[3];
    const float* W2       = (const float*)d_in[4];
    const float* b2       = (const float*)d_in[5];
    const float* Vw       = (const float*)d_in[6];
    const float* bv       = (const float*)d_in[7];

    float* ctx_out = (float*)d_out;
    float* w_out   = (float*)d_out + (size_t)BATCH * EDIM;

    float* ph = (float*)d_ws;
    unsigned short* F1 = (unsigned short*)(ph + (size_t)BATCH * UDIM);
    unsigned short* F2 = F1 + (size_t)8 * 32 * 64 * 8;

    prep_frag<<<dim3(96), dim3(256), 0, stream>>>(W1, W2, F1, F2);
    prep_ph<<<dim3(128), dim3(256), 0, stream>>>(hidden, F2, b1, b2, ph);
    attn_main<<<dim3(BATCH), dim3(512), 0, stream>>>(
        features, F1, ph, Vw, bv, ctx_out, w_out);
}